// Round 1
// baseline (2144.587 us; speedup 1.0000x reference)
//
#include <hip/hip_runtime.h>
#include <math.h>

typedef __bf16 bf16;
typedef __bf16 bf16x8 __attribute__((ext_vector_type(8)));
typedef float f32x4 __attribute__((ext_vector_type(4)));

#define ZDIM 17728
#define HIDN 4096
#define BSZ 128
#define KC1 24   // K-split chunks for GEMM1 (554 k-steps of 32)
#define KC2 4    // K-split chunks for GEMM2 (128 k-steps of 32)

__device__ __forceinline__ void gl_lds16(const bf16* g, bf16* l) {
  __builtin_amdgcn_global_load_lds(
      (const __attribute__((address_space(1))) unsigned int*)g,
      (__attribute__((address_space(3))) unsigned int*)l, 16, 0, 0);
}

// ---------- cast + transpose: src (K x N) f32 -> dst (N x K) bf16 ----------
// Tile: 64 K-rows x 32 N-cols. Each thread writes 8B (4 packed bf16 k-values).
__global__ void k_cast_transpose(const float* __restrict__ src, bf16* __restrict__ dst,
                                 int K, int N) {
  __shared__ float t[64][33];
  int tx = threadIdx.x, ty = threadIdx.y;  // 32 x 8
  int tid = ty * 32 + tx;
  int n0 = blockIdx.x * 32, k0 = blockIdx.y * 64;
#pragma unroll
  for (int i = 0; i < 64; i += 8)
    t[ty + i][tx] = src[(size_t)(k0 + ty + i) * N + (n0 + tx)];
  __syncthreads();
  int nl = tid >> 4;          // 0..15
  int kk = (tid & 15) * 4;    // 0,4,...,60
#pragma unroll
  for (int p = 0; p < 2; ++p) {
    int nn = nl + p * 16;
    union { bf16 h[4]; unsigned long long u; } pk;
    pk.h[0] = (bf16)t[kk + 0][nn];
    pk.h[1] = (bf16)t[kk + 1][nn];
    pk.h[2] = (bf16)t[kk + 2][nn];
    pk.h[3] = (bf16)t[kk + 3][nn];
    *(unsigned long long*)&dst[(size_t)(n0 + nn) * K + k0 + kk] = pk.u;
  }
}

// ---------- build z0 (fp32 into d_out, bf16 copy) ----------
__global__ void k_build_z0(const float* __restrict__ input_freq, const int* __restrict__ seq,
                           const int* __restrict__ uid, const float* __restrict__ fuse,
                           const int* __restrict__ n_poi_p,
                           float* __restrict__ z, bf16* __restrict__ zb) {
  int n = blockIdx.x * 256 + threadIdx.x;
  int b = blockIdx.y;
  if (n >= ZDIM) return;
  float v;
  if (n < 9408) {
    v = input_freq[b * 3136 + (n % 3136)];
  } else if (n < 17600) {
    int m = n - 9408;
    int d = m >> 6, l = m & 63;
    v = fuse[(size_t)seq[b * 64 + l] * 128 + d];
  } else {
    int d = n - 17600;
    v = fuse[(size_t)(n_poi_p[0] + uid[b]) * 128 + d];
  }
  size_t idx = (size_t)b * ZDIM + n;
  z[idx] = v;
  zb[idx] = (bf16)v;
}

// ---------- time grid + sin/cos embedding: E[12][128][6] ----------
__global__ void k_build_emb(const float* __restrict__ cur, const float* __restrict__ tar,
                            float* __restrict__ E) {
  int b = threadIdx.x;  // 128 threads
  const float P[3] = {24.0f, 7.0f, 365.0f};
  const float TWO_PI = 6.283185307179586f;
  float t[3];
  for (int c = 0; c < 3; ++c) t[c] = cur[b * 3 + c];
  int r = 0;
  for (int j = 0; j < 3; ++j) {
    float s = cur[b * 3 + j], e = tar[b * 3 + j];
    bool wrap = s > e;
    float ea = wrap ? (e + P[j]) : e;
    for (int k = 0; k < 4; ++k) {
      float frac = (float)k / 3.0f;
      float v = s + (ea - s) * frac;
      if (wrap) v = v - floorf(v / P[j]) * P[j];
      t[j] = v;
      for (int c = 0; c < 3; ++c) {
        float ph = TWO_PI * t[c] / P[c];
        E[(r * BSZ + b) * 6 + c] = sinf(ph);
        E[(r * BSZ + b) * 6 + 3 + c] = cosf(ph);
      }
      ++r;
    }
  }
}

// ---------- GEMM1 partial: P[kc] = A(128 x Kchunk) * W1t^T ----------
// Double-buffered LDS: prefetch k-step s+1 while computing s; ONE barrier/step.
__global__ __launch_bounds__(256, 3) void k_gemm1(const bf16* __restrict__ A,
                                                  const bf16* __restrict__ Bt,
                                                  float* __restrict__ P) {
  __shared__ __align__(16) bf16 As[2][128 * 32];
  __shared__ __align__(16) bf16 Bs[2][128 * 32];
  const int tid = threadIdx.x;
  const int w = tid >> 6, lane = tid & 63;
  const int q = lane >> 4, r = lane & 15;
  const int nt = blockIdx.x, kc = blockIdx.y;
  const int nsteps = 23 + (kc < 2 ? 1 : 0);
  const int kstart = kc * 23 + (kc < 2 ? kc : 2);

  const int srow = lane >> 2, sslot = lane & 3;
  const int sg = sslot ^ ((srow >> 2) & 3);
  const int rA0 = (2 * w) * 16 + srow;
  const int rA1 = (2 * w + 1) * 16 + srow;
  long k0 = (long)kstart * 32;
  const bf16* pA0 = A + (size_t)rA0 * ZDIM + k0 + sg * 8;
  const bf16* pA1 = A + (size_t)rA1 * ZDIM + k0 + sg * 8;
  const bf16* pB0 = Bt + (size_t)(nt * 128 + rA0) * ZDIM + k0 + sg * 8;
  const bf16* pB1 = Bt + (size_t)(nt * 128 + rA1) * ZDIM + k0 + sg * 8;
  const int la0 = (2 * w) * 512;
  const int la1 = la0 + 512;

  const int swr = (r >> 2) & 3;
  const int aoff = r * 32 + (q ^ swr) * 8;
  const int boff0 = (32 * w + r) * 32 + (q ^ swr) * 8;
  const int boff1 = boff0 + 512;

  f32x4 zero4 = {0.f, 0.f, 0.f, 0.f};
  f32x4 acc[8][2];
#pragma unroll
  for (int mb = 0; mb < 8; ++mb) { acc[mb][0] = zero4; acc[mb][1] = zero4; }

  // prologue: stage k-step 0 into buffer 0
  gl_lds16(pA0, &As[0][la0]); gl_lds16(pA1, &As[0][la1]);
  gl_lds16(pB0, &Bs[0][la0]); gl_lds16(pB1, &Bs[0][la1]);
  pA0 += 32; pA1 += 32; pB0 += 32; pB1 += 32;
  __syncthreads();

  int cur = 0;
  for (int s = 0; s < nsteps; ++s) {
    int nxt = cur ^ 1;
    if (s + 1 < nsteps) {
      gl_lds16(pA0, &As[nxt][la0]); gl_lds16(pA1, &As[nxt][la1]);
      gl_lds16(pB0, &Bs[nxt][la0]); gl_lds16(pB1, &Bs[nxt][la1]);
      pA0 += 32; pA1 += 32; pB0 += 32; pB1 += 32;
    }
    bf16x8 bfr0 = *(const bf16x8*)&Bs[cur][boff0];
    bf16x8 bfr1 = *(const bf16x8*)&Bs[cur][boff1];
#pragma unroll
    for (int mb = 0; mb < 8; ++mb) {
      bf16x8 afr = *(const bf16x8*)&As[cur][mb * 512 + aoff];
      acc[mb][0] = __builtin_amdgcn_mfma_f32_16x16x32_bf16(afr, bfr0, acc[mb][0], 0, 0, 0);
      acc[mb][1] = __builtin_amdgcn_mfma_f32_16x16x32_bf16(afr, bfr1, acc[mb][1], 0, 0, 0);
    }
    __syncthreads();  // drains vmcnt(0): prefetched loads land; LDS reads done
    cur = nxt;
  }

  float* Pk = P + (size_t)kc * (BSZ * HIDN);
#pragma unroll
  for (int i = 0; i < 2; ++i) {
    int n = nt * 128 + (2 * w + i) * 16 + r;
#pragma unroll
    for (int mb = 0; mb < 8; ++mb) {
#pragma unroll
      for (int reg = 0; reg < 4; ++reg) {
        int brow = mb * 16 + q * 4 + reg;
        Pk[(size_t)brow * HIDN + n] = acc[mb][i][reg];
      }
    }
  }
}

// ---------- reduce partials + b1 + emb-correction + tanh -> Hb (bf16) ----------
// Vectorized x4: each thread produces 4 consecutive n.
__global__ void k_epi1(const float* __restrict__ P, const float* __restrict__ b1,
                       const float* __restrict__ W1, const float* __restrict__ E,
                       int step, bf16* __restrict__ Hb) {
  int idx = blockIdx.x * 256 + threadIdx.x;  // 128*4096/4 = 131072 threads
  int base = idx * 4;
  int b = base >> 12, n = base & 4095;
  f32x4 s = *(const f32x4*)&b1[n];
#pragma unroll
  for (int c = 0; c < KC1; ++c)
    s += *(const f32x4*)&P[((size_t)c * BSZ + b) * HIDN + n];
  const float* e0 = E + ((size_t)step * BSZ + b) * 6;
  const float* e1 = e0 + BSZ * 6;
#pragma unroll
  for (int j = 0; j < 6; ++j) {
    f32x4 w0 = *(const f32x4*)&W1[(size_t)(ZDIM + j) * HIDN + n];
    f32x4 w1 = *(const f32x4*)&W1[(size_t)(ZDIM + 6 + j) * HIDN + n];
    s += e0[j] * w0;
    s += e1[j] * w1;
  }
  union { bf16 h[4]; unsigned long long u; } pk;
#pragma unroll
  for (int i = 0; i < 4; ++i) pk.h[i] = (bf16)tanhf(s[i]);
  *(unsigned long long*)&Hb[base] = pk.u;
}

// ---------- GEMM2 partial: P2[kc] = Hb(128 x Kchunk) * W2t^T ----------
// Double-buffered LDS, one barrier per k-step.
__global__ __launch_bounds__(256, 4) void k_gemm2(const bf16* __restrict__ A,
                                                  const bf16* __restrict__ Bt,
                                                  float* __restrict__ P2) {
  __shared__ __align__(16) bf16 As[2][128 * 32];
  __shared__ __align__(16) bf16 Bs[2][64 * 32];
  const int tid = threadIdx.x;
  const int w = tid >> 6, lane = tid & 63;
  const int q = lane >> 4, r = lane & 15;
  const int nt = blockIdx.x;   // 0..276
  const int kc = blockIdx.y;   // 0..KC2-1
  const long k0 = (long)kc * 32 * 32;  // 32 k-steps per chunk

  const int srow = lane >> 2, sslot = lane & 3;
  const int sg = sslot ^ ((srow >> 2) & 3);
  const int rA0 = (2 * w) * 16 + srow;
  const int rA1 = (2 * w + 1) * 16 + srow;
  const int rB = w * 16 + srow;
  const bf16* pA0 = A + (size_t)rA0 * HIDN + k0 + sg * 8;
  const bf16* pA1 = A + (size_t)rA1 * HIDN + k0 + sg * 8;
  const bf16* pB = Bt + (size_t)(nt * 64 + rB) * HIDN + k0 + sg * 8;
  const int la0 = (2 * w) * 512;
  const int la1 = la0 + 512;
  const int lb = w * 512;

  const int swr = (r >> 2) & 3;
  const int aoff = r * 32 + (q ^ swr) * 8;
  const int boff = (w * 16 + r) * 32 + (q ^ swr) * 8;

  f32x4 zero4 = {0.f, 0.f, 0.f, 0.f};
  f32x4 acc[8];
#pragma unroll
  for (int mb = 0; mb < 8; ++mb) acc[mb] = zero4;

  // prologue
  gl_lds16(pA0, &As[0][la0]); gl_lds16(pA1, &As[0][la1]); gl_lds16(pB, &Bs[0][lb]);
  pA0 += 32; pA1 += 32; pB += 32;
  __syncthreads();

  int cur = 0;
  for (int s = 0; s < 32; ++s) {
    int nxt = cur ^ 1;
    if (s < 31) {
      gl_lds16(pA0, &As[nxt][la0]); gl_lds16(pA1, &As[nxt][la1]); gl_lds16(pB, &Bs[nxt][lb]);
      pA0 += 32; pA1 += 32; pB += 32;
    }
    bf16x8 bfr = *(const bf16x8*)&Bs[cur][boff];
#pragma unroll
    for (int mb = 0; mb < 8; ++mb) {
      bf16x8 afr = *(const bf16x8*)&As[cur][mb * 512 + aoff];
      acc[mb] = __builtin_amdgcn_mfma_f32_16x16x32_bf16(afr, bfr, acc[mb], 0, 0, 0);
    }
    __syncthreads();
    cur = nxt;
  }

  float* Pk = P2 + (size_t)kc * (BSZ * ZDIM);
  int n = nt * 64 + w * 16 + r;
#pragma unroll
  for (int mb = 0; mb < 8; ++mb) {
#pragma unroll
    for (int reg = 0; reg < 4; ++reg) {
      int brow = mb * 16 + q * 4 + reg;
      Pk[(size_t)brow * ZDIM + n] = acc[mb][reg];
    }
  }
}

// ---------- reduce GEMM2 partials + b2, update z, write zb ----------
// Vectorized x4.
__global__ void k_epi2(const float* __restrict__ P2, const float* __restrict__ b2,
                       float* __restrict__ z, bf16* __restrict__ zb) {
  int idx = blockIdx.x * 256 + threadIdx.x;  // 128*17728/4 = 567296 threads
  size_t base = (size_t)idx * 4;
  int n = (int)(base % ZDIM);
  f32x4 s = *(const f32x4*)&b2[n];
#pragma unroll
  for (int c = 0; c < KC2; ++c)
    s += *(const f32x4*)&P2[(size_t)c * (BSZ * ZDIM) + base];
  f32x4 v = *(const f32x4*)&z[base];
  v += s;
  *(f32x4*)&z[base] = v;
  union { bf16 h[4]; unsigned long long u; } pk;
#pragma unroll
  for (int i = 0; i < 4; ++i) pk.h[i] = (bf16)v[i];
  *(unsigned long long*)&zb[base] = pk.u;
}

extern "C" void kernel_launch(void* const* d_in, const int* in_sizes, int n_in,
                              void* d_out, int out_size, void* d_ws, size_t ws_size,
                              hipStream_t stream) {
  const float* input_freq = (const float*)d_in[0];
  const int* seq = (const int*)d_in[1];
  const int* uid = (const int*)d_in[2];
  const float* cur = (const float*)d_in[3];
  const float* tar = (const float*)d_in[4];
  const float* fuse = (const float*)d_in[5];
  const float* W1 = (const float*)d_in[6];
  const float* b1 = (const float*)d_in[7];
  const float* W2 = (const float*)d_in[8];
  const float* b2 = (const float*)d_in[9];
  const int* n_poi = (const int*)d_in[10];
  float* z = (float*)d_out;

  char* ws = (char*)d_ws;
  bf16* W1t = (bf16*)ws;                              // 4096 x 17728 bf16 = 145,227,776 B
  bf16* W2t = (bf16*)(ws + 145227776);                // 17728 x 4096 bf16 = 145,227,776 B
  bf16* Zb = (bf16*)(ws + 290455552);                 // 128 x 17728 bf16
  bf16* Hb = (bf16*)(ws + 294993920);                 // 128 x 4096 bf16
  float* P = (float*)(ws + 296042496);                // KC1 x 128 x 4096 f32 = 50,331,648 B
  float* P2 = (float*)(ws + 296042496 + 50331648);    // KC2 x 128 x 17728 f32 = 36,306,944 B
  float* E = (float*)(ws + 296042496 + 50331648 + 36306944);  // 12 x 128 x 6 f32

  k_cast_transpose<<<dim3(HIDN / 32, ZDIM / 64), dim3(32, 8), 0, stream>>>(W1, W1t, ZDIM, HIDN);
  k_cast_transpose<<<dim3(ZDIM / 32, HIDN / 64), dim3(32, 8), 0, stream>>>(W2, W2t, HIDN, ZDIM);
  k_build_z0<<<dim3(70, BSZ), 256, 0, stream>>>(input_freq, seq, uid, fuse, n_poi, z, Zb);
  k_build_emb<<<1, BSZ, 0, stream>>>(cur, tar, E);

  for (int s = 0; s < 11; ++s) {
    k_gemm1<<<dim3(32, KC1), 256, 0, stream>>>(Zb, W1t, P);
    k_epi1<<<512, 256, 0, stream>>>(P, b1, W1, E, s, Hb);
    k_gemm2<<<dim3(277, KC2), 256, 0, stream>>>(Hb, W2t, P2);
    k_epi2<<<2216, 256, 0, stream>>>(P2, b2, z, Zb);
  }
}

// Round 2
// 2042.358 us; speedup vs baseline: 1.0501x; 1.0501x over previous
//
#include <hip/hip_runtime.h>
#include <math.h>

typedef __bf16 bf16;
typedef __bf16 bf16x8 __attribute__((ext_vector_type(8)));
typedef float f32x4 __attribute__((ext_vector_type(4)));

#define ZDIM 17728
#define HIDN 4096
#define BSZ 128
#define KC1 24    // K-split chunks for GEMM1 (554 k-steps of 32)
#define KC2 4     // K-split chunks for GEMM2 (128 k-steps of 32)
#define N2PAD 17792  // 139*128 — GEMM2 N padded to a multiple of 128

__device__ __forceinline__ void gl_lds16(const bf16* g, bf16* l) {
  __builtin_amdgcn_global_load_lds(
      (const __attribute__((address_space(1))) unsigned int*)g,
      (__attribute__((address_space(3))) unsigned int*)l, 16, 0, 0);
}

// ---------- cast + transpose: src (K x N) f32 -> dst (N x K) bf16 ----------
__global__ void k_cast_transpose(const float* __restrict__ src, bf16* __restrict__ dst,
                                 int K, int N) {
  __shared__ float t[64][33];
  int tx = threadIdx.x, ty = threadIdx.y;  // 32 x 8
  int tid = ty * 32 + tx;
  int n0 = blockIdx.x * 32, k0 = blockIdx.y * 64;
#pragma unroll
  for (int i = 0; i < 64; i += 8)
    t[ty + i][tx] = src[(size_t)(k0 + ty + i) * N + (n0 + tx)];
  __syncthreads();
  int nl = tid >> 4;          // 0..15
  int kk = (tid & 15) * 4;    // 0,4,...,60
#pragma unroll
  for (int p = 0; p < 2; ++p) {
    int nn = nl + p * 16;
    union { bf16 h[4]; unsigned long long u; } pk;
    pk.h[0] = (bf16)t[kk + 0][nn];
    pk.h[1] = (bf16)t[kk + 1][nn];
    pk.h[2] = (bf16)t[kk + 2][nn];
    pk.h[3] = (bf16)t[kk + 3][nn];
    *(unsigned long long*)&dst[(size_t)(n0 + nn) * K + k0 + kk] = pk.u;
  }
}

// ---------- zero fill (8B chunks) for W2t pad rows ----------
__global__ void k_zero8(unsigned long long* __restrict__ p, int n8) {
  int i = blockIdx.x * 256 + threadIdx.x;
  if (i < n8) p[i] = 0ull;
}

// ---------- build z0 (fp32 into d_out, bf16 copy) ----------
__global__ void k_build_z0(const float* __restrict__ input_freq, const int* __restrict__ seq,
                           const int* __restrict__ uid, const float* __restrict__ fuse,
                           const int* __restrict__ n_poi_p,
                           float* __restrict__ z, bf16* __restrict__ zb) {
  int n = blockIdx.x * 256 + threadIdx.x;
  int b = blockIdx.y;
  if (n >= ZDIM) return;
  float v;
  if (n < 9408) {
    v = input_freq[b * 3136 + (n % 3136)];
  } else if (n < 17600) {
    int m = n - 9408;
    int d = m >> 6, l = m & 63;
    v = fuse[(size_t)seq[b * 64 + l] * 128 + d];
  } else {
    int d = n - 17600;
    v = fuse[(size_t)(n_poi_p[0] + uid[b]) * 128 + d];
  }
  size_t idx = (size_t)b * ZDIM + n;
  z[idx] = v;
  zb[idx] = (bf16)v;
}

// ---------- time grid + sin/cos embedding: E[12][128][6] ----------
__global__ void k_build_emb(const float* __restrict__ cur, const float* __restrict__ tar,
                            float* __restrict__ E) {
  int b = threadIdx.x;  // 128 threads
  const float P[3] = {24.0f, 7.0f, 365.0f};
  const float TWO_PI = 6.283185307179586f;
  float t[3];
  for (int c = 0; c < 3; ++c) t[c] = cur[b * 3 + c];
  int r = 0;
  for (int j = 0; j < 3; ++j) {
    float s = cur[b * 3 + j], e = tar[b * 3 + j];
    bool wrap = s > e;
    float ea = wrap ? (e + P[j]) : e;
    for (int k = 0; k < 4; ++k) {
      float frac = (float)k / 3.0f;
      float v = s + (ea - s) * frac;
      if (wrap) v = v - floorf(v / P[j]) * P[j];
      t[j] = v;
      for (int c = 0; c < 3; ++c) {
        float ph = TWO_PI * t[c] / P[c];
        E[(r * BSZ + b) * 6 + c] = sinf(ph);
        E[(r * BSZ + b) * 6 + 3 + c] = cosf(ph);
      }
      ++r;
    }
  }
}

// ---------- unified split-K GEMM partial: P[kc] = A(128 x Kchunk) * Bt^T ----------
// 128x128 output tile, BK=32. 3-stage LDS pipeline, counted vmcnt (T4):
// loads for step s+1/s+2 stay in flight across barriers; never drain to 0 in main loop.
__global__ __launch_bounds__(256, 3) void k_gemm(const bf16* __restrict__ A,
                                                 const bf16* __restrict__ Bt,
                                                 float* __restrict__ P,
                                                 int lda, int ldp,
                                                 int nbase, int nextra) {
  __shared__ __align__(16) bf16 As[3][128 * 32];
  __shared__ __align__(16) bf16 Bs[3][128 * 32];
  const int tid = threadIdx.x;
  const int w = tid >> 6, lane = tid & 63;
  const int q = lane >> 4, r = lane & 15;
  const int nt = blockIdx.x, kc = blockIdx.y;
  const int nsteps = nbase + (kc < nextra ? 1 : 0);
  const int kstart = kc * nbase + (kc < nextra ? kc : nextra);

  const int srow = lane >> 2, sslot = lane & 3;
  const int sg = sslot ^ ((srow >> 2) & 3);
  const int rA0 = (2 * w) * 16 + srow;
  const int rA1 = (2 * w + 1) * 16 + srow;
  long k0 = (long)kstart * 32;
  const bf16* pA0 = A + (size_t)rA0 * lda + k0 + sg * 8;
  const bf16* pA1 = A + (size_t)rA1 * lda + k0 + sg * 8;
  const bf16* pB0 = Bt + (size_t)(nt * 128 + rA0) * lda + k0 + sg * 8;
  const bf16* pB1 = Bt + (size_t)(nt * 128 + rA1) * lda + k0 + sg * 8;
  const int la0 = (2 * w) * 512;
  const int la1 = la0 + 512;

  const int swr = (r >> 2) & 3;
  const int aoff = r * 32 + (q ^ swr) * 8;
  const int boff0 = (32 * w + r) * 32 + (q ^ swr) * 8;
  const int boff1 = boff0 + 512;

  f32x4 zero4 = {0.f, 0.f, 0.f, 0.f};
  f32x4 acc[8][2];
#pragma unroll
  for (int mb = 0; mb < 8; ++mb) { acc[mb][0] = zero4; acc[mb][1] = zero4; }

#define ISSUE(ib)                                                          \
  {                                                                        \
    gl_lds16(pA0, &As[ib][la0]); gl_lds16(pA1, &As[ib][la1]);              \
    gl_lds16(pB0, &Bs[ib][la0]); gl_lds16(pB1, &Bs[ib][la1]);              \
    pA0 += 32; pA1 += 32; pB0 += 32; pB1 += 32;                            \
  }

#define COMPUTE(ib)                                                        \
  {                                                                        \
    bf16x8 bfr0 = *(const bf16x8*)&Bs[ib][boff0];                          \
    bf16x8 bfr1 = *(const bf16x8*)&Bs[ib][boff1];                          \
    _Pragma("unroll")                                                      \
    for (int mb = 0; mb < 8; ++mb) {                                       \
      bf16x8 afr = *(const bf16x8*)&As[ib][mb * 512 + aoff];               \
      acc[mb][0] = __builtin_amdgcn_mfma_f32_16x16x32_bf16(afr, bfr0, acc[mb][0], 0, 0, 0); \
      acc[mb][1] = __builtin_amdgcn_mfma_f32_16x16x32_bf16(afr, bfr1, acc[mb][1], 0, 0, 0); \
    }                                                                      \
  }

  // prologue: 2-deep prefetch
  ISSUE(0); ISSUE(1);
  const int nmain = nsteps - 2;
  for (int s = 0; s < nmain; ++s) {
    ISSUE((s + 2) % 3);
    // allow the 8 newest loads (steps s+1, s+2) to stay in flight; step s landed
    asm volatile("s_waitcnt vmcnt(8)" ::: "memory");
    __builtin_amdgcn_s_barrier();
    COMPUTE(s % 3);
    asm volatile("" ::: "memory");
    __builtin_amdgcn_s_barrier();  // reads of buf s%3 done before iter s+1 overwrites it
  }
  // tail step nsteps-2: 4 loads (last step) still in flight
  asm volatile("s_waitcnt vmcnt(4)" ::: "memory");
  __builtin_amdgcn_s_barrier();
  COMPUTE(nmain % 3);
  asm volatile("" ::: "memory");
  __builtin_amdgcn_s_barrier();
  // tail step nsteps-1: drain
  asm volatile("s_waitcnt vmcnt(0)" ::: "memory");
  __builtin_amdgcn_s_barrier();
  COMPUTE((nmain + 1) % 3);

#undef ISSUE
#undef COMPUTE

  float* Pk = P + (size_t)kc * (BSZ * ldp);
#pragma unroll
  for (int i = 0; i < 2; ++i) {
    int n = nt * 128 + (2 * w + i) * 16 + r;
#pragma unroll
    for (int mb = 0; mb < 8; ++mb) {
#pragma unroll
      for (int reg = 0; reg < 4; ++reg) {
        int brow = mb * 16 + q * 4 + reg;
        Pk[(size_t)brow * ldp + n] = acc[mb][i][reg];
      }
    }
  }
}

// ---------- reduce partials + b1 + emb-correction + tanh -> Hb (bf16) ----------
__global__ void k_epi1(const float* __restrict__ P, const float* __restrict__ b1,
                       const float* __restrict__ W1, const float* __restrict__ E,
                       int step, bf16* __restrict__ Hb) {
  int idx = blockIdx.x * 256 + threadIdx.x;  // 131072 threads
  int base = idx * 4;
  int b = base >> 12, n = base & 4095;
  f32x4 s = *(const f32x4*)&b1[n];
#pragma unroll
  for (int c = 0; c < KC1; ++c)
    s += *(const f32x4*)&P[((size_t)c * BSZ + b) * HIDN + n];
  const float* e0 = E + ((size_t)step * BSZ + b) * 6;
  const float* e1 = e0 + BSZ * 6;
#pragma unroll
  for (int j = 0; j < 6; ++j) {
    f32x4 w0 = *(const f32x4*)&W1[(size_t)(ZDIM + j) * HIDN + n];
    f32x4 w1 = *(const f32x4*)&W1[(size_t)(ZDIM + 6 + j) * HIDN + n];
    s += e0[j] * w0;
    s += e1[j] * w1;
  }
  union { bf16 h[4]; unsigned long long u; } pk;
#pragma unroll
  for (int i = 0; i < 4; ++i) pk.h[i] = (bf16)tanhf(s[i]);
  *(unsigned long long*)&Hb[base] = pk.u;
}

// ---------- reduce GEMM2 partials + b2, update z, write zb ----------
// P2 rows have stride N2PAD; z/zb are dense ZDIM.
__global__ void k_epi2(const float* __restrict__ P2, const float* __restrict__ b2,
                       float* __restrict__ z, bf16* __restrict__ zb) {
  int idx = blockIdx.x * 256 + threadIdx.x;  // 567296 threads
  size_t base = (size_t)idx * 4;
  int b = (int)(base / ZDIM);
  int n = (int)(base % ZDIM);
  f32x4 s = *(const f32x4*)&b2[n];
  size_t poff = (size_t)b * N2PAD + n;
#pragma unroll
  for (int c = 0; c < KC2; ++c)
    s += *(const f32x4*)&P2[(size_t)c * (BSZ * N2PAD) + poff];
  f32x4 v = *(const f32x4*)&z[base];
  v += s;
  *(f32x4*)&z[base] = v;
  union { bf16 h[4]; unsigned long long u; } pk;
#pragma unroll
  for (int i = 0; i < 4; ++i) pk.h[i] = (bf16)v[i];
  *(unsigned long long*)&zb[base] = pk.u;
}

extern "C" void kernel_launch(void* const* d_in, const int* in_sizes, int n_in,
                              void* d_out, int out_size, void* d_ws, size_t ws_size,
                              hipStream_t stream) {
  const float* input_freq = (const float*)d_in[0];
  const int* seq = (const int*)d_in[1];
  const int* uid = (const int*)d_in[2];
  const float* cur = (const float*)d_in[3];
  const float* tar = (const float*)d_in[4];
  const float* fuse = (const float*)d_in[5];
  const float* W1 = (const float*)d_in[6];
  const float* b1 = (const float*)d_in[7];
  const float* W2 = (const float*)d_in[8];
  const float* b2 = (const float*)d_in[9];
  const int* n_poi = (const int*)d_in[10];
  float* z = (float*)d_out;

  char* ws = (char*)d_ws;
  bf16* W1t = (bf16*)ws;                               // 4096 x 17728 bf16  = 145,227,776 B
  bf16* W2t = (bf16*)(ws + 145227776);                 // 17792 x 4096 bf16  = 145,752,064 B
  bf16* Zb = (bf16*)(ws + 290979840);                  // 128 x 17728 bf16   = 4,538,368 B
  bf16* Hb = (bf16*)(ws + 295518208);                  // 128 x 4096 bf16    = 1,048,576 B
  float* P = (float*)(ws + 296566784);                 // KC1 x 128 x 4096 f32 = 50,331,648 B
  float* P2 = (float*)(ws + 346898432);                // KC2 x 128 x 17792 f32 = 36,438,016 B
  float* E = (float*)(ws + 383336448);                 // 12 x 128 x 6 f32

  k_cast_transpose<<<dim3(HIDN / 32, ZDIM / 64), dim3(32, 8), 0, stream>>>(W1, W1t, ZDIM, HIDN);
  k_cast_transpose<<<dim3(ZDIM / 32, HIDN / 64), dim3(32, 8), 0, stream>>>(W2, W2t, HIDN, ZDIM);
  // zero W2t pad rows [17728, 17792): 64*4096 bf16 = 65536 x 8B
  k_zero8<<<256, 256, 0, stream>>>((unsigned long long*)(W2t + (size_t)ZDIM * HIDN), 65536);
  k_build_z0<<<dim3(70, BSZ), 256, 0, stream>>>(input_freq, seq, uid, fuse, n_poi, z, Zb);
  k_build_emb<<<1, BSZ, 0, stream>>>(cur, tar, E);

  for (int s = 0; s < 11; ++s) {
    k_gemm<<<dim3(32, KC1), 256, 0, stream>>>(Zb, W1t, P, ZDIM, HIDN, 23, 2);
    k_epi1<<<512, 256, 0, stream>>>(P, b1, W1, E, s, Hb);
    k_gemm<<<dim3(N2PAD / 128, KC2), 256, 0, stream>>>(Hb, W2t, P2, HIDN, N2PAD, 32, 0);
    k_epi2<<<2216, 256, 0, stream>>>(P2, b2, z, Zb);
  }
}